// Round 3
// baseline (187.345 us; speedup 1.0000x reference)
//
#include <hip/hip_runtime.h>

typedef __bf16 bf16x8 __attribute__((ext_vector_type(8)));
typedef float f32x4 __attribute__((ext_vector_type(4)));
typedef unsigned short u16;
typedef u16 u16x8 __attribute__((ext_vector_type(8)));

#define TID ((int)threadIdx.x)

constexpr int Nn = 64, Tt = 300, Vv = 25;
constexpr int Fin = 1600;           // V*C = V*CO
constexpr int RowsT = 19200;        // N*T
constexpr int TBR = 16;             // t-rows per block
constexpr int NTB = 19;             // ceil(300/16)
constexpr int RAWE = 64 * TBR * Vv; // 25600 bf16 elements (51200 B)
constexpr int YP = 21;              // ylds row stride (odd -> coprime with banks)
constexpr int NREP = 8;             // wsum replicas
constexpr int SBLK = 608;           // k_stats blocks (2 tiles each)
constexpr float EPSv = 1e-5f;

// d_ws layout:
//   [0, 102400)        wsum: 8 replicas x (1600 sum + 1600 sumsq) f32
//   [102400, 307200)   wv:   Wv fragments bf16[25*2*4*512]
//   [307200, 310400)   offs: u16[1600] raw-LDS gather offsets
constexpr int WS_WV   = 102400;
constexpr int WS_OFFS = 307200;

__device__ __forceinline__ u16 f2b(float f) {
  unsigned u = __float_as_uint(f);
  return (u16)((u + 0x7fffu + ((u >> 16) & 1u)) >> 16); // RNE
}
__device__ __forceinline__ float b2f(u16 h) {
  return __uint_as_float(((unsigned)h) << 16);
}
__device__ __forceinline__ unsigned long long pack4(float a, float b, float c, float d) {
  return (unsigned long long)f2b(a)
       | ((unsigned long long)f2b(b) << 16)
       | ((unsigned long long)f2b(c) << 32)
       | ((unsigned long long)f2b(d) << 48);
}

// ---- stage x-tile as bf16, layout [c][t*25+v] (512 threads) ----
__device__ __forceinline__ void stage_raw(const float* __restrict__ x,
                                          int n, int t0, int validg, u16* raw) {
  const int base = n * 480000 + t0 * 25;
  if (validg == TBR * 25) {
    #pragma unroll
    for (int i = 0; i < 13; ++i) {
      int q = TID + i * 512;              // float4 group id, 0..6399
      if (q < 6400) {
        int c = q / 100;
        int g4 = (q - c * 100) * 4;       // 16B aligned
        float4 xv = *reinterpret_cast<const float4*>(x + base + c * 7500 + g4);
        *reinterpret_cast<unsigned long long*>(raw + q * 4) = pack4(xv.x, xv.y, xv.z, xv.w);
      }
    }
  } else {
    #pragma unroll
    for (int i = 0; i < 13; ++i) {
      int q = TID + i * 512;
      if (q < 6400) {
        int c = q / 100;
        int g4 = (q - c * 100) * 4;
        float4 xv = make_float4(0.f, 0.f, 0.f, 0.f);
        if (g4 < validg)                  // validg==300: 4-groups all-or-nothing
          xv = *reinterpret_cast<const float4*>(x + base + c * 7500 + g4);
        *reinterpret_cast<unsigned long long*>(raw + q * 4) = pack4(xv.x, xv.y, xv.z, xv.w);
      }
    }
  }
}

// B fragment (Wv) direct from global (L2-hot), fragment-major layout
__device__ __forceinline__ bf16x8 loadB(const u16* __restrict__ wv,
                                        int v, int ks, int nt, int l) {
  return *reinterpret_cast<const bf16x8*>(wv + ((((v * 2 + ks) * 4) + nt) << 9) + l * 8);
}

// A fragment: pure LDS gather; t=lane&15, k-slice = ks*32+grp*8+i
__device__ __forceinline__ bf16x8 build_a(const u16* raw, const u16* __restrict__ offs,
                                          int v, int ks, int t, int grp) {
  int jb = v * 64 + ks * 32 + grp * 8;          // multiple of 8 -> 16B aligned
  u16x8 o = *reinterpret_cast<const u16x8*>(offs + jb);
  u16x8 a;
  #pragma unroll
  for (int i = 0; i < 8; ++i) a[i] = raw[(int)o[i] + t * 25];
  return *reinterpret_cast<bf16x8*>(&a);
}

// ---- precompute: zero wsum, gather offsets, Wv = (tanh(fm)+1)*W in frag layout ----
__global__ void k_wv(const float* __restrict__ lin_w, const float* __restrict__ feat_mask,
                     const int* __restrict__ shift_in, float* __restrict__ wsum,
                     u16* __restrict__ wv, u16* __restrict__ offs) {
  int gid = blockIdx.x * 256 + TID;     // 0..12799
  wsum[gid] = 0.f;
  wsum[gid + 12800] = 0.f;
  if (gid < Fin) {
    int s = shift_in[gid];
    offs[gid] = (u16)((s & 63) * 400 + (s >> 6));
  }
  int v = blockIdx.x >> 1, ks = blockIdx.x & 1;
  int nt = (TID >> 6) & 3, l = TID & 63;
  int c0 = ks * 32 + (l >> 4) * 8;
  int d = nt * 16 + (l & 15);
  u16x8 o8;
  #pragma unroll
  for (int i = 0; i < 8; ++i) {
    int c = c0 + i;
    float m = tanhf(feat_mask[v * 64 + c]) + 1.0f;
    o8[i] = f2b(m * lin_w[c * 64 + d]);
  }
  *reinterpret_cast<u16x8*>(wv + ((((v * 2 + ks) * 4) + nt) << 9) + l * 8) = o8;
}

__global__ __launch_bounds__(512, 4) void k_stats(
    const float* __restrict__ x, const u16* __restrict__ wv,
    const u16* __restrict__ offs, float* __restrict__ wsum)
{
  __shared__ __align__(16) u16 raw[RAWE];
  int bid = blockIdx.x;                 // 0..607, 2 tiles each
  int w = TID >> 6, l = TID & 63;
  int t_lane = l & 15, grp = l >> 4;
  float p[4][4] = {{0}}, q[4][4] = {{0}};

  #pragma unroll
  for (int half = 0; half < 2; ++half) {
    int tile = bid + half * SBLK;       // 0..1215
    int n = tile / NTB, tb = tile - n * NTB;
    int t0 = tb * TBR;
    int validg = min(TBR, Tt - t0) * 25;
    if (half) __syncthreads();          // raw reuse fence
    stage_raw(x, n, t0, validg, raw);
    __syncthreads();
    #pragma unroll
    for (int k = 0; k < 4; ++k) {
      int v = w + 8 * k;
      if (v < Vv) {
        bf16x8 a0 = build_a(raw, offs, v, 0, t_lane, grp);
        bf16x8 a1 = build_a(raw, offs, v, 1, t_lane, grp);
        #pragma unroll
        for (int nt = 0; nt < 4; ++nt) {
          f32x4 acc = {0.f, 0.f, 0.f, 0.f};
          acc = __builtin_amdgcn_mfma_f32_16x16x32_bf16(a0, loadB(wv, v, 0, nt, l), acc, 0, 0, 0);
          acc = __builtin_amdgcn_mfma_f32_16x16x32_bf16(a1, loadB(wv, v, 1, nt, l), acc, 0, 0, 0);
          p[k][nt] += acc[0] + acc[1] + acc[2] + acc[3];
          q[k][nt] += acc[0]*acc[0] + acc[1]*acc[1] + acc[2]*acc[2] + acc[3]*acc[3];
        }
      }
    }
  }
  // one reduce + atomic round per block, into bid&7 replica
  float* ws_r = wsum + (bid & (NREP - 1)) * 3200;
  #pragma unroll
  for (int k = 0; k < 4; ++k) {
    int v = w + 8 * k;
    if (v < Vv) {
      #pragma unroll
      for (int nt = 0; nt < 4; ++nt) {
        float pp = p[k][nt], qq = q[k][nt];
        pp += __shfl_xor(pp, 16); pp += __shfl_xor(pp, 32);
        qq += __shfl_xor(qq, 16); qq += __shfl_xor(qq, 32);
        if ((l & 48) == 0) {
          int col = v * 64 + nt * 16 + (l & 15);
          atomicAdd(&ws_r[col], pp);
          atomicAdd(&ws_r[1600 + col], qq);
        }
      }
    }
  }
}

__global__ __launch_bounds__(512, 4) void k_main(
    const float* __restrict__ x, const u16* __restrict__ wv,
    const u16* __restrict__ offs, const float* __restrict__ wsum,
    const float* __restrict__ gamma, const float* __restrict__ beta,
    const int* __restrict__ shift_out, float* __restrict__ out)
{
  // [0,51200) raw -> later ylds bf16[1600*21] = [0,67200) ; epi [67200,80000)
  __shared__ __align__(16) unsigned char smem[80000];
  u16* raw  = reinterpret_cast<u16*>(smem);
  u16* ylds = reinterpret_cast<u16*>(smem);
  unsigned long long* epi = reinterpret_cast<unsigned long long*>(smem + 67200);

  int bid = blockIdx.x;
  int n = bid / NTB, tb = bid - n * NTB;
  int t0 = tb * TBR;
  int validg = min(TBR, Tt - t0) * 25;

  stage_raw(x, n, t0, validg, raw);

  // BN fold (k_epi inlined): entry {f32 scale, bf16 off, u16 s2*YP} at perm index d*25+v
  #pragma unroll
  for (int i = 0; i < 4; ++i) {
    int j = TID + i * 512;
    if (j < Fin) {
      int s2 = shift_out[j];
      float sm = 0.f, sq = 0.f;
      #pragma unroll
      for (int r = 0; r < NREP; ++r) {
        sm += wsum[r * 3200 + s2];
        sq += wsum[r * 3200 + 1600 + s2];
      }
      sm *= (1.0f / RowsT);
      sq *= (1.0f / RowsT);
      float rstd = rsqrtf(fmaxf(sq - sm * sm, 0.f) + EPSv);
      float sc = gamma[j] * rstd;             // lin_b provably cancels in BN
      int d = j & 63, v = j >> 6;
      epi[d * 25 + v] = (unsigned long long)__float_as_uint(sc)
                      | ((unsigned long long)f2b(beta[j] - sm * sc) << 32)
                      | ((unsigned long long)(unsigned)(s2 * YP) << 48);
    }
  }
  __syncthreads();

  // hoist A fragments to registers; raw dies after this
  int w = TID >> 6, l = TID & 63, grp = l >> 4, t_lane = l & 15;
  bf16x8 areg[4][2];
  #pragma unroll
  for (int k = 0; k < 4; ++k) {
    int v = w + 8 * k;
    if (v < Vv) {
      areg[k][0] = build_a(raw, offs, v, 0, t_lane, grp);
      areg[k][1] = build_a(raw, offs, v, 1, t_lane, grp);
    }
  }
  __syncthreads();  // overlay region now ylds

  #pragma unroll
  for (int k = 0; k < 4; ++k) {
    int v = w + 8 * k;
    if (v < Vv) {
      #pragma unroll
      for (int nt = 0; nt < 4; ++nt) {
        f32x4 acc = {0.f, 0.f, 0.f, 0.f};
        acc = __builtin_amdgcn_mfma_f32_16x16x32_bf16(areg[k][0], loadB(wv, v, 0, nt, l), acc, 0, 0, 0);
        acc = __builtin_amdgcn_mfma_f32_16x16x32_bf16(areg[k][1], loadB(wv, v, 1, nt, l), acc, 0, 0, 0);
        int o = (v * 64 + nt * 16 + t_lane) * YP + grp * 4;  // rows t = grp*4+j
        #pragma unroll
        for (int j = 0; j < 4; ++j) ylds[o + j] = f2b(acc[j]);
      }
    }
  }
  __syncthreads();

  // epilogue: BN + residual (x re-read, L3-hot) + relu, float4 stores
  const int obase = n * 480000 + t0 * 25;
  #pragma unroll
  for (int it = 0; it < 13; ++it) {
    int g = TID + it * 512;               // float4 group id
    if (g < 6400) {
      int d = g / 100;
      int f0 = (g - d * 100) * 4;
      if (f0 < validg) {
        const float4 xr = *reinterpret_cast<const float4*>(x + obase + d * 7500 + f0);
        float4 o;
        float* op = &o.x;
        const float* xp = &xr.x;
        #pragma unroll
        for (int e = 0; e < 4; ++e) {
          int f = f0 + e;
          int t = f / 25;
          int v = f - t * 25;
          unsigned long long ep = epi[d * 25 + v];
          float sc = __uint_as_float((unsigned)ep);
          float of = b2f((u16)(ep >> 32));
          float y = b2f(ylds[(int)(ep >> 48) + t]);
          op[e] = fmaxf(fmaf(y, sc, of) + xp[e], 0.f);
        }
        *reinterpret_cast<float4*>(out + obase + d * 7500 + f0) = o;
      }
    }
  }
}

extern "C" void kernel_launch(void* const* d_in, const int* in_sizes, int n_in,
                              void* d_out, int out_size, void* d_ws, size_t ws_size,
                              hipStream_t stream) {
  (void)in_sizes; (void)n_in; (void)out_size; (void)ws_size;
  const float* x        = (const float*)d_in[0];
  const float* lin_w    = (const float*)d_in[1];
  // d_in[2] = lin_b: provably cancels in BatchNorm -> unused
  const float* feat_mask= (const float*)d_in[3];
  const float* gamma    = (const float*)d_in[4];
  const float* beta     = (const float*)d_in[5];
  const int*   shift_in = (const int*)d_in[6];
  const int*   shift_out= (const int*)d_in[7];
  float* wsum = (float*)d_ws;
  u16*   wv   = (u16*)((char*)d_ws + WS_WV);
  u16*   offs = (u16*)((char*)d_ws + WS_OFFS);

  k_wv   <<<50, 256, 0, stream>>>(lin_w, feat_mask, shift_in, wsum, wv, offs);
  k_stats<<<SBLK, 512, 0, stream>>>(x, wv, offs, wsum);
  k_main <<<Nn * NTB, 512, 0, stream>>>(x, wv, offs, wsum, gamma, beta, shift_out,
                                        (float*)d_out);
}

// Round 4
// 153.087 us; speedup vs baseline: 1.2238x; 1.2238x over previous
//
#include <hip/hip_runtime.h>

typedef __bf16 bf16x8 __attribute__((ext_vector_type(8)));
typedef float f32x4 __attribute__((ext_vector_type(4)));
typedef unsigned short u16;
typedef unsigned int u32;
typedef unsigned long long u64;
typedef u16 u16x8 __attribute__((ext_vector_type(8)));

#define TID ((int)threadIdx.x)

constexpr int Nn = 64, Tt = 300, Vv = 25;
constexpr int Fin = 1600;           // V*C = V*CO
constexpr int RowsT = 19200;        // N*T
constexpr int TBR = 16;             // t-rows per block
constexpr int NTB = 19;             // ceil(300/16)
constexpr int RAWE = 64 * TBR * Vv; // 25600 bf16 (51200 B)
constexpr int YP = 21;              // ylds row stride (odd -> bank-coprime)
constexpr int NREP = 16;            // wsum atomic replicas
constexpr int SBLK = 608;           // k_stats blocks (2 tiles each)
constexpr float EPSv = 1e-5f;

// d_ws layout:
//   [0, 204800)           wsum: 16 replicas x (1600 sum + 1600 sumsq) f32
//   [204800, 217600)      epi_g: u64[1600] folded BN, permuted to d*25+v
//   [217600, 225792)      wv:    u16[4096] plain-W B-fragments (v-independent)
//   [225792, 232192)      combo_g: u32[1600] (gather_off<<16)|bf16(tanh(fm)+1)
constexpr int WS_EPI   = 204800;
constexpr int WS_WV    = 217600;
constexpr int WS_COMBO = 225792;

__device__ __forceinline__ u16 f2b(float f) {
  u32 u = __float_as_uint(f);
  return (u16)((u + 0x7fffu + ((u >> 16) & 1u)) >> 16); // RNE
}
__device__ __forceinline__ float b2f(u16 h) {
  return __uint_as_float(((u32)h) << 16);
}
__device__ __forceinline__ u64 pack4(float a, float b, float c, float d) {
  return (u64)f2b(a) | ((u64)f2b(b) << 16) | ((u64)f2b(c) << 32) | ((u64)f2b(d) << 48);
}

// ---- stage x-tile as bf16, layout [c][t*25+v] (512 threads) ----
__device__ __forceinline__ void stage_raw(const float* __restrict__ x,
                                          int n, int t0, int validg, u16* raw) {
  const int base = n * 480000 + t0 * 25;
  if (validg == TBR * 25) {
    #pragma unroll
    for (int i = 0; i < 13; ++i) {
      int q = TID + i * 512;              // float4 group id, 0..6399
      if (q < 6400) {
        int c = q / 100;
        int g4 = (q - c * 100) * 4;       // 16B aligned
        float4 xv = *reinterpret_cast<const float4*>(x + base + c * 7500 + g4);
        *reinterpret_cast<u64*>(raw + q * 4) = pack4(xv.x, xv.y, xv.z, xv.w);
      }
    }
  } else {
    #pragma unroll
    for (int i = 0; i < 13; ++i) {
      int q = TID + i * 512;
      if (q < 6400) {
        int c = q / 100;
        int g4 = (q - c * 100) * 4;
        float4 xv = make_float4(0.f, 0.f, 0.f, 0.f);
        if (g4 < validg)                  // validg==300: 4-groups all-or-nothing
          xv = *reinterpret_cast<const float4*>(x + base + c * 7500 + g4);
        *reinterpret_cast<u64*>(raw + q * 4) = pack4(xv.x, xv.y, xv.z, xv.w);
      }
    }
  }
}

// 8 v-independent B fragments (plain W) -> registers, one coalesced pass
__device__ __forceinline__ void load_bfr_g(const u16* __restrict__ wv, bf16x8 bfr[2][4]) {
  int l = TID & 63;
  #pragma unroll
  for (int ks = 0; ks < 2; ++ks)
    #pragma unroll
    for (int nt = 0; nt < 4; ++nt)
      bfr[ks][nt] = *reinterpret_cast<const bf16x8*>(wv + ((((ks << 2) | nt) << 9) + l * 8));
}

// A fragment: gather+mask from LDS; t=lane&15, k-slice = ks*32+grp*8+i
__device__ __forceinline__ bf16x8 build_a(const u16* raw, const u32* combo,
                                          int v, int ks, int t, int grp) {
  int jb = v * 64 + ks * 32 + grp * 8;
  bf16x8 a;
  #pragma unroll
  for (int i = 0; i < 8; ++i) {
    u32 cb = combo[jb + i];
    float m = __uint_as_float((cb & 0xffffu) << 16);
    float xv = b2f(raw[(cb >> 16) + t * 25]);
    a[i] = (__bf16)(xv * m);
  }
  return a;
}

// ---- precompute: zero wsum; combo (tanh hoisted here); plain-W B fragments ----
__global__ void k_wv(const float* __restrict__ lin_w, const float* __restrict__ feat_mask,
                     const int* __restrict__ shift_in, float* __restrict__ wsum,
                     u16* __restrict__ wv, u32* __restrict__ combo_g) {
  int gid = blockIdx.x * 256 + TID;       // grid 13*256 = 3328
  #pragma unroll
  for (int i = 0; i < 16; ++i) {
    int z = gid + i * 3328;
    if (z < NREP * 3200) wsum[z] = 0.f;
  }
  if (gid < Fin) {
    int s = shift_in[gid];                               // source col v2*64+c2
    u32 off = (u32)((s & 63) * 400 + (s >> 6));          // raw idx c2*400 + v2
    float m = tanhf(feat_mask[gid]) + 1.0f;
    combo_g[gid] = (off << 16) | (u32)f2b(m);
  }
  if (gid >= 2048 && gid < 2560) {        // 512 threads build B fragments
    int t = gid - 2048;
    int l = t & 63, nt = (t >> 6) & 3, ks = t >> 8;
    int c0 = ks * 32 + (l >> 4) * 8, d = nt * 16 + (l & 15);
    u16x8 o8;
    #pragma unroll
    for (int i = 0; i < 8; ++i) o8[i] = f2b(lin_w[(c0 + i) * 64 + d]);
    *reinterpret_cast<u16x8*>(wv + ((((ks << 2) | nt) << 9) + l * 8)) = o8;
  }
}

__global__ __launch_bounds__(512, 4) void k_stats(
    const float* __restrict__ x, const u16* __restrict__ wv,
    const u32* __restrict__ combo_g, float* __restrict__ wsum)
{
  __shared__ __align__(16) u16 raw[RAWE];
  __shared__ __align__(16) u32 combo[Fin];
  bf16x8 bfr[2][4];
  load_bfr_g(wv, bfr);
  #pragma unroll
  for (int i = 0; i < 4; ++i) {
    int j = TID + i * 512;
    if (j < Fin) combo[j] = combo_g[j];
  }

  int bid = blockIdx.x;                   // 0..607, 2 tiles each
  int w = TID >> 6, l = TID & 63;
  int t_lane = l & 15, grp = l >> 4;
  float p[4][4] = {{0}}, q[4][4] = {{0}};

  #pragma unroll
  for (int half = 0; half < 2; ++half) {
    int tile = bid + half * SBLK;         // 0..1215
    int n = tile / NTB, tb = tile - n * NTB;
    int t0 = tb * TBR;
    int validg = min(TBR, Tt - t0) * 25;
    if (half) __syncthreads();            // raw reuse fence
    stage_raw(x, n, t0, validg, raw);
    __syncthreads();
    #pragma unroll
    for (int k = 0; k < 4; ++k) {
      int v = w + 8 * k;
      if (v < Vv) {
        bf16x8 a0 = build_a(raw, combo, v, 0, t_lane, grp);
        bf16x8 a1 = build_a(raw, combo, v, 1, t_lane, grp);
        #pragma unroll
        for (int nt = 0; nt < 4; ++nt) {
          f32x4 acc = {0.f, 0.f, 0.f, 0.f};
          acc = __builtin_amdgcn_mfma_f32_16x16x32_bf16(a0, bfr[0][nt], acc, 0, 0, 0);
          acc = __builtin_amdgcn_mfma_f32_16x16x32_bf16(a1, bfr[1][nt], acc, 0, 0, 0);
          // zero-padded t rows contribute 0 to both sums
          p[k][nt] += acc[0] + acc[1] + acc[2] + acc[3];
          q[k][nt] += acc[0]*acc[0] + acc[1]*acc[1] + acc[2]*acc[2] + acc[3]*acc[3];
        }
      }
    }
  }
  // one reduce + atomic round per block, into bid&15 replica
  float* ws_r = wsum + (bid & (NREP - 1)) * 3200;
  #pragma unroll
  for (int k = 0; k < 4; ++k) {
    int v = w + 8 * k;
    if (v < Vv) {
      #pragma unroll
      for (int nt = 0; nt < 4; ++nt) {
        float pp = p[k][nt], qq = q[k][nt];
        pp += __shfl_xor(pp, 16); pp += __shfl_xor(pp, 32);
        qq += __shfl_xor(qq, 16); qq += __shfl_xor(qq, 32);
        if ((l & 48) == 0) {
          int col = v * 64 + nt * 16 + (l & 15);
          atomicAdd(&ws_r[col], pp);
          atomicAdd(&ws_r[1600 + col], qq);
        }
      }
    }
  }
}

// BN fold once: entry {f32 scale, bf16 off, u16 s2*YP} at permuted index d*25+v
__global__ void k_epi(const float* __restrict__ wsum, const float* __restrict__ gamma,
                      const float* __restrict__ beta, const int* __restrict__ shift_out,
                      u64* __restrict__ epi_g) {
  int k = blockIdx.x * 256 + TID;
  if (k >= Fin) return;
  int s2 = shift_out[k];
  float sm = 0.f, sq = 0.f;
  #pragma unroll
  for (int r = 0; r < NREP; ++r) {
    sm += wsum[r * 3200 + s2];
    sq += wsum[r * 3200 + 1600 + s2];
  }
  sm *= (1.0f / RowsT);
  sq *= (1.0f / RowsT);
  float rstd = rsqrtf(fmaxf(sq - sm * sm, 0.f) + EPSv);
  float sc = gamma[k] * rstd;             // lin_b provably cancels in BN
  int d = k & 63, v = k >> 6;
  epi_g[d * 25 + v] = (u64)__float_as_uint(sc)
                    | ((u64)f2b(beta[k] - sm * sc) << 32)
                    | ((u64)(u32)(s2 * YP) << 48);
}

__global__ __launch_bounds__(512, 4) void k_main(
    const float* __restrict__ x, const u16* __restrict__ wv,
    const u32* __restrict__ combo_g, const u64* __restrict__ epi_g,
    float* __restrict__ out)
{
  // [0,51200) raw | [51200,57600) combo  --(after hoist sync)--> ylds [0,67200)
  // epi [67200,80000) persistent
  __shared__ __align__(16) unsigned char smem[80000];
  u16* raw   = reinterpret_cast<u16*>(smem);
  u32* combo = reinterpret_cast<u32*>(smem + 51200);
  u16* ylds  = reinterpret_cast<u16*>(smem);
  u64* epi   = reinterpret_cast<u64*>(smem + 67200);

  int bid = blockIdx.x;
  int n = bid / NTB, tb = bid - n * NTB;
  int t0 = tb * TBR;
  int validg = min(TBR, Tt - t0) * 25;

  bf16x8 bfr[2][4];
  load_bfr_g(wv, bfr);
  stage_raw(x, n, t0, validg, raw);
  #pragma unroll
  for (int i = 0; i < 4; ++i) {
    int j = TID + i * 512;
    if (j < Fin) {
      combo[j] = combo_g[j];
      epi[j] = epi_g[j];
    }
  }
  __syncthreads();

  // hoist A fragments to registers; raw+combo die after this
  int w = TID >> 6, l = TID & 63, grp = l >> 4, t_lane = l & 15;
  bf16x8 areg[4][2];
  #pragma unroll
  for (int k = 0; k < 4; ++k) {
    int v = w + 8 * k;
    if (v < Vv) {
      areg[k][0] = build_a(raw, combo, v, 0, t_lane, grp);
      areg[k][1] = build_a(raw, combo, v, 1, t_lane, grp);
    }
  }
  __syncthreads();  // overlay region now ylds

  #pragma unroll
  for (int k = 0; k < 4; ++k) {
    int v = w + 8 * k;
    if (v < Vv) {
      #pragma unroll
      for (int nt = 0; nt < 4; ++nt) {
        f32x4 acc = {0.f, 0.f, 0.f, 0.f};
        acc = __builtin_amdgcn_mfma_f32_16x16x32_bf16(areg[k][0], bfr[0][nt], acc, 0, 0, 0);
        acc = __builtin_amdgcn_mfma_f32_16x16x32_bf16(areg[k][1], bfr[1][nt], acc, 0, 0, 0);
        int o = (v * 64 + nt * 16 + t_lane) * YP + grp * 4;   // rows t = grp*4+j
        #pragma unroll
        for (int j = 0; j < 4; ++j) ylds[o + j] = f2b(acc[j]);
      }
    }
  }
  __syncthreads();

  // epilogue: BN + residual (x re-read, L3-hot) + relu, float4 stores
  const int obase = n * 480000 + t0 * 25;
  #pragma unroll
  for (int it = 0; it < 13; ++it) {
    int g = TID + it * 512;               // float4 group id
    if (g < 6400) {
      int d = g / 100;
      int f0 = (g - d * 100) * 4;
      if (f0 < validg) {
        const float4 xr = *reinterpret_cast<const float4*>(x + obase + d * 7500 + f0);
        float4 o;
        float* op = &o.x;
        const float* xp = &xr.x;
        #pragma unroll
        for (int e = 0; e < 4; ++e) {
          int f = f0 + e;
          int t = f / 25;
          int v = f - t * 25;
          u64 ep = epi[d * 25 + v];
          float sc = __uint_as_float((u32)ep);
          float of = b2f((u16)(ep >> 32));
          float y = b2f(ylds[(int)(ep >> 48) + t]);
          op[e] = fmaxf(fmaf(y, sc, of) + xp[e], 0.f);
        }
        *reinterpret_cast<float4*>(out + obase + d * 7500 + f0) = o;
      }
    }
  }
}

extern "C" void kernel_launch(void* const* d_in, const int* in_sizes, int n_in,
                              void* d_out, int out_size, void* d_ws, size_t ws_size,
                              hipStream_t stream) {
  (void)in_sizes; (void)n_in; (void)out_size; (void)ws_size;
  const float* x        = (const float*)d_in[0];
  const float* lin_w    = (const float*)d_in[1];
  // d_in[2] = lin_b: provably cancels in BatchNorm -> unused
  const float* feat_mask= (const float*)d_in[3];
  const float* gamma    = (const float*)d_in[4];
  const float* beta     = (const float*)d_in[5];
  const int*   shift_in = (const int*)d_in[6];
  const int*   shift_out= (const int*)d_in[7];
  float* wsum   = (float*)d_ws;
  u64*   epi_g  = (u64*)((char*)d_ws + WS_EPI);
  u16*   wv     = (u16*)((char*)d_ws + WS_WV);
  u32*   combo_g= (u32*)((char*)d_ws + WS_COMBO);

  k_wv   <<<13, 256, 0, stream>>>(lin_w, feat_mask, shift_in, wsum, wv, combo_g);
  k_stats<<<SBLK, 512, 0, stream>>>(x, wv, combo_g, wsum);
  k_epi  <<<7, 256, 0, stream>>>(wsum, gamma, beta, shift_out, epi_g);
  k_main <<<Nn * NTB, 512, 0, stream>>>(x, wv, combo_g, epi_g, (float*)d_out);
}

// Round 5
// 146.148 us; speedup vs baseline: 1.2819x; 1.0475x over previous
//
#include <hip/hip_runtime.h>

typedef __bf16 bf16x8 __attribute__((ext_vector_type(8)));
typedef float f32x4 __attribute__((ext_vector_type(4)));
typedef unsigned short u16;
typedef unsigned int u32;
typedef unsigned long long u64;
typedef u16 u16x8 __attribute__((ext_vector_type(8)));

#define TID ((int)threadIdx.x)

constexpr int Nn = 64, Tt = 300, Vv = 25;
constexpr int Fin = 1600;           // V*C = V*CO
constexpr int RowsT = 19200;        // N*T
constexpr int TBR = 16;             // t-rows per block
constexpr int NTB = 19;             // ceil(300/16)
constexpr int RAWE = 64 * TBR * Vv; // 25600 bf16 (51200 B)
constexpr int YP = 21;              // ylds row stride (odd -> bank-coprime)
constexpr int NREP = 16;            // wsum atomic replicas
constexpr float EPSv = 1e-5f;

// d_ws layout:
//   [0, 204800)           wsum: 16 replicas x (1600 sum + 1600 sumsq) f32
//   [204800, 217600)      epi_g: u64[1600] folded BN, permuted to d*25+v
//   [217600, 225792)      wv:    u16[4096] plain-W B-fragments (v-independent)
//   [225792, 232192)      combo_g: u32[1600] (gather_off<<16)|bf16(tanh(fm)+1)
constexpr int WS_EPI   = 204800;
constexpr int WS_WV    = 217600;
constexpr int WS_COMBO = 225792;

__device__ __forceinline__ u16 f2b(float f) {
  u32 u = __float_as_uint(f);
  return (u16)((u + 0x7fffu + ((u >> 16) & 1u)) >> 16); // RNE
}
__device__ __forceinline__ float b2f(u16 h) {
  return __uint_as_float(((u32)h) << 16);
}
__device__ __forceinline__ u64 pack4(float a, float b, float c, float d) {
  return (u64)f2b(a) | ((u64)f2b(b) << 16) | ((u64)f2b(c) << 32) | ((u64)f2b(d) << 48);
}

// ---- stage x-tile as bf16, layout [c][t*25+v] (512 threads) ----
__device__ __forceinline__ void stage_raw(const float* __restrict__ x,
                                          int n, int t0, int validg, u16* raw) {
  const int base = n * 480000 + t0 * 25;
  if (validg == TBR * 25) {
    #pragma unroll
    for (int i = 0; i < 13; ++i) {
      int q = TID + i * 512;              // float4 group id, 0..6399
      if (q < 6400) {
        int c = q / 100;
        int g4 = (q - c * 100) * 4;       // 16B aligned
        float4 xv = *reinterpret_cast<const float4*>(x + base + c * 7500 + g4);
        *reinterpret_cast<u64*>(raw + q * 4) = pack4(xv.x, xv.y, xv.z, xv.w);
      }
    }
  } else {
    #pragma unroll
    for (int i = 0; i < 13; ++i) {
      int q = TID + i * 512;
      if (q < 6400) {
        int c = q / 100;
        int g4 = (q - c * 100) * 4;
        float4 xv = make_float4(0.f, 0.f, 0.f, 0.f);
        if (g4 < validg)                  // validg==300: 4-groups all-or-nothing
          xv = *reinterpret_cast<const float4*>(x + base + c * 7500 + g4);
        *reinterpret_cast<u64*>(raw + q * 4) = pack4(xv.x, xv.y, xv.z, xv.w);
      }
    }
  }
}

// 8 v-independent B fragments (plain W) -> registers, one coalesced pass
__device__ __forceinline__ void load_bfr_g(const u16* __restrict__ wv, bf16x8 bfr[2][4]) {
  int l = TID & 63;
  #pragma unroll
  for (int ks = 0; ks < 2; ++ks)
    #pragma unroll
    for (int nt = 0; nt < 4; ++nt)
      bfr[ks][nt] = *reinterpret_cast<const bf16x8*>(wv + ((((ks << 2) | nt) << 9) + l * 8));
}

// A fragment: gather+mask from LDS; combo table from L2; t=lane&15
__device__ __forceinline__ bf16x8 build_a(const u16* raw, const u32* __restrict__ combo,
                                          int v, int ks, int t, int grp) {
  int jb = v * 64 + ks * 32 + grp * 8;    // multiple of 8 -> 2x dwordx4
  bf16x8 a;
  #pragma unroll
  for (int i = 0; i < 8; ++i) {
    u32 cb = combo[jb + i];
    float m = __uint_as_float((cb & 0xffffu) << 16);
    float xv = b2f(raw[(cb >> 16) + t * 25]);
    a[i] = (__bf16)(xv * m);
  }
  return a;
}

// ---- precompute: zero wsum; combo (tanh hoisted here); plain-W B fragments ----
__global__ void k_wv(const float* __restrict__ lin_w, const float* __restrict__ feat_mask,
                     const int* __restrict__ shift_in, float* __restrict__ wsum,
                     u16* __restrict__ wv, u32* __restrict__ combo_g) {
  int gid = blockIdx.x * 256 + TID;       // grid 13*256 = 3328
  #pragma unroll
  for (int i = 0; i < 16; ++i) {
    int z = gid + i * 3328;
    if (z < NREP * 3200) wsum[z] = 0.f;
  }
  if (gid < Fin) {
    int s = shift_in[gid];                               // source col v2*64+c2
    u32 off = (u32)((s & 63) * 400 + (s >> 6));          // raw idx c2*400 + v2
    float m = tanhf(feat_mask[gid]) + 1.0f;
    combo_g[gid] = (off << 16) | (u32)f2b(m);
  }
  if (gid >= 2048 && gid < 2560) {        // 512 threads build B fragments
    int t = gid - 2048;
    int l = t & 63, nt = (t >> 6) & 3, ks = t >> 8;
    int c0 = ks * 32 + (l >> 4) * 8, d = nt * 16 + (l & 15);
    u16x8 o8;
    #pragma unroll
    for (int i = 0; i < 8; ++i) o8[i] = f2b(lin_w[(c0 + i) * 64 + d]);
    *reinterpret_cast<u16x8*>(wv + ((((ks << 2) | nt) << 9) + l * 8)) = o8;
  }
}

__global__ __launch_bounds__(512, 6) void k_stats(
    const float* __restrict__ x, const u16* __restrict__ wv,
    const u32* __restrict__ combo_g, float* __restrict__ wsum)
{
  __shared__ __align__(16) u16 raw[RAWE];   // 51.2 KB only -> 3 blocks/CU
  bf16x8 bfr[2][4];
  load_bfr_g(wv, bfr);

  int bid = blockIdx.x;                   // 0..1215, 1 tile each
  int n = bid / NTB, tb = bid - n * NTB;
  int t0 = tb * TBR;
  int validg = min(TBR, Tt - t0) * 25;
  int w = TID >> 6, l = TID & 63;
  int t_lane = l & 15, grp = l >> 4;

  stage_raw(x, n, t0, validg, raw);
  __syncthreads();

  float p[4][4], q[4][4];
  #pragma unroll
  for (int k = 0; k < 4; ++k) {
    int v = w + 8 * k;
    if (v < Vv) {
      bf16x8 a0 = build_a(raw, combo_g, v, 0, t_lane, grp);
      bf16x8 a1 = build_a(raw, combo_g, v, 1, t_lane, grp);
      #pragma unroll
      for (int nt = 0; nt < 4; ++nt) {
        f32x4 acc = {0.f, 0.f, 0.f, 0.f};
        acc = __builtin_amdgcn_mfma_f32_16x16x32_bf16(a0, bfr[0][nt], acc, 0, 0, 0);
        acc = __builtin_amdgcn_mfma_f32_16x16x32_bf16(a1, bfr[1][nt], acc, 0, 0, 0);
        // zero-padded t rows contribute 0 to both sums
        p[k][nt] = acc[0] + acc[1] + acc[2] + acc[3];
        q[k][nt] = acc[0]*acc[0] + acc[1]*acc[1] + acc[2]*acc[2] + acc[3]*acc[3];
      }
    }
  }
  // one reduce + atomic round per block, into bid&15 replica
  float* ws_r = wsum + (bid & (NREP - 1)) * 3200;
  #pragma unroll
  for (int k = 0; k < 4; ++k) {
    int v = w + 8 * k;
    if (v < Vv) {
      #pragma unroll
      for (int nt = 0; nt < 4; ++nt) {
        float pp = p[k][nt], qq = q[k][nt];
        pp += __shfl_xor(pp, 16); pp += __shfl_xor(pp, 32);
        qq += __shfl_xor(qq, 16); qq += __shfl_xor(qq, 32);
        if ((l & 48) == 0) {
          int col = v * 64 + nt * 16 + (l & 15);
          atomicAdd(&ws_r[col], pp);
          atomicAdd(&ws_r[1600 + col], qq);
        }
      }
    }
  }
}

// BN fold once: entry {f32 scale, bf16 off, u16 s2*YP} at permuted index d*25+v
__global__ void k_epi(const float* __restrict__ wsum, const float* __restrict__ gamma,
                      const float* __restrict__ beta, const int* __restrict__ shift_out,
                      u64* __restrict__ epi_g) {
  int k = blockIdx.x * 256 + TID;
  if (k >= Fin) return;
  int s2 = shift_out[k];
  float sm = 0.f, sq = 0.f;
  #pragma unroll
  for (int r = 0; r < NREP; ++r) {
    sm += wsum[r * 3200 + s2];
    sq += wsum[r * 3200 + 1600 + s2];
  }
  sm *= (1.0f / RowsT);
  sq *= (1.0f / RowsT);
  float rstd = rsqrtf(fmaxf(sq - sm * sm, 0.f) + EPSv);
  float sc = gamma[k] * rstd;             // lin_b provably cancels in BN
  int d = k & 63, v = k >> 6;
  epi_g[d * 25 + v] = (u64)__float_as_uint(sc)
                    | ((u64)f2b(beta[k] - sm * sc) << 32)
                    | ((u64)(u32)(s2 * YP) << 48);
}

__global__ __launch_bounds__(512, 4) void k_main(
    const float* __restrict__ x, const u16* __restrict__ wv,
    const u32* __restrict__ combo_g, const u64* __restrict__ epi_g,
    float* __restrict__ out)
{
  // [0,51200) raw | [51200,57600) combo  --(after hoist sync)--> ylds [0,67200)
  // epi [67200,80000) persistent
  __shared__ __align__(16) unsigned char smem[80000];
  u16* raw   = reinterpret_cast<u16*>(smem);
  u32* combo = reinterpret_cast<u32*>(smem + 51200);
  u16* ylds  = reinterpret_cast<u16*>(smem);
  u64* epi   = reinterpret_cast<u64*>(smem + 67200);

  int bid = blockIdx.x;
  int n = bid / NTB, tb = bid - n * NTB;
  int t0 = tb * TBR;
  int validg = min(TBR, Tt - t0) * 25;

  bf16x8 bfr[2][4];
  load_bfr_g(wv, bfr);
  stage_raw(x, n, t0, validg, raw);
  #pragma unroll
  for (int i = 0; i < 4; ++i) {
    int j = TID + i * 512;
    if (j < Fin) {
      combo[j] = combo_g[j];
      epi[j] = epi_g[j];
    }
  }
  __syncthreads();

  // hoist A fragments to registers; raw+combo die after this
  int w = TID >> 6, l = TID & 63, grp = l >> 4, t_lane = l & 15;
  bf16x8 areg[4][2];
  #pragma unroll
  for (int k = 0; k < 4; ++k) {
    int v = w + 8 * k;
    if (v < Vv) {
      areg[k][0] = build_a(raw, combo, v, 0, t_lane, grp);
      areg[k][1] = build_a(raw, combo, v, 1, t_lane, grp);
    }
  }
  __syncthreads();  // overlay region now ylds

  #pragma unroll
  for (int k = 0; k < 4; ++k) {
    int v = w + 8 * k;
    if (v < Vv) {
      #pragma unroll
      for (int nt = 0; nt < 4; ++nt) {
        f32x4 acc = {0.f, 0.f, 0.f, 0.f};
        acc = __builtin_amdgcn_mfma_f32_16x16x32_bf16(areg[k][0], bfr[0][nt], acc, 0, 0, 0);
        acc = __builtin_amdgcn_mfma_f32_16x16x32_bf16(areg[k][1], bfr[1][nt], acc, 0, 0, 0);
        int o = (v * 64 + nt * 16 + t_lane) * YP + grp * 4;   // rows t = grp*4+j
        #pragma unroll
        for (int j = 0; j < 4; ++j) ylds[o + j] = f2b(acc[j]);
      }
    }
  }
  __syncthreads();

  // epilogue: BN + residual (x re-read, L3-hot) + relu, float4 stores
  const int obase = n * 480000 + t0 * 25;
  #pragma unroll
  for (int it = 0; it < 13; ++it) {
    int g = TID + it * 512;               // float4 group id
    if (g < 6400) {
      int d = g / 100;
      int f0 = (g - d * 100) * 4;
      if (f0 < validg) {
        const float4 xr = *reinterpret_cast<const float4*>(x + obase + d * 7500 + f0);
        float4 o;
        float* op = &o.x;
        const float* xp = &xr.x;
        #pragma unroll
        for (int e = 0; e < 4; ++e) {
          int f = f0 + e;
          int t = f / 25;
          int v = f - t * 25;
          u64 ep = epi[d * 25 + v];
          float sc = __uint_as_float((u32)ep);
          float of = b2f((u16)(ep >> 32));
          float y = b2f(ylds[(int)(ep >> 48) + t]);
          op[e] = fmaxf(fmaf(y, sc, of) + xp[e], 0.f);
        }
        *reinterpret_cast<float4*>(out + obase + d * 7500 + f0) = o;
      }
    }
  }
}

extern "C" void kernel_launch(void* const* d_in, const int* in_sizes, int n_in,
                              void* d_out, int out_size, void* d_ws, size_t ws_size,
                              hipStream_t stream) {
  (void)in_sizes; (void)n_in; (void)out_size; (void)ws_size;
  const float* x        = (const float*)d_in[0];
  const float* lin_w    = (const float*)d_in[1];
  // d_in[2] = lin_b: provably cancels in BatchNorm -> unused
  const float* feat_mask= (const float*)d_in[3];
  const float* gamma    = (const float*)d_in[4];
  const float* beta     = (const float*)d_in[5];
  const int*   shift_in = (const int*)d_in[6];
  const int*   shift_out= (const int*)d_in[7];
  float* wsum   = (float*)d_ws;
  u64*   epi_g  = (u64*)((char*)d_ws + WS_EPI);
  u16*   wv     = (u16*)((char*)d_ws + WS_WV);
  u32*   combo_g= (u32*)((char*)d_ws + WS_COMBO);

  k_wv   <<<13, 256, 0, stream>>>(lin_w, feat_mask, shift_in, wsum, wv, combo_g);
  k_stats<<<Nn * NTB, 512, 0, stream>>>(x, wv, combo_g, wsum);
  k_epi  <<<7, 256, 0, stream>>>(wsum, gamma, beta, shift_out, epi_g);
  k_main <<<Nn * NTB, 512, 0, stream>>>(x, wv, combo_g, epi_g, (float*)d_out);
}

// Round 6
// 111.544 us; speedup vs baseline: 1.6796x; 1.3102x over previous
//
#include <hip/hip_runtime.h>

typedef __bf16 bf16x8 __attribute__((ext_vector_type(8)));
typedef float f32x4 __attribute__((ext_vector_type(4)));
typedef unsigned short u16;
typedef unsigned int u32;
typedef unsigned long long u64;
typedef u16 u16x8 __attribute__((ext_vector_type(8)));

#define TID ((int)threadIdx.x)

constexpr int Nn = 64, Tt = 300, Vv = 25;
constexpr int Fin = 1600;           // V*C = V*CO
constexpr int RowsT = 19200;        // N*T
constexpr int TBR = 16;             // t-rows per block
constexpr int NTB = 19;             // ceil(300/16)
constexpr int NBLK = Nn * NTB;      // 1216 tiles
constexpr int RAWE = 64 * TBR * Vv; // 25600 bf16 (51200 B)
constexpr int YP = 21;              // ylds row stride (odd -> bank-coprime)
constexpr float EPSv = 1e-5f;

// d_ws layout:
//   [0, 12800)        wsum_final: 1600 sum + 1600 sumsq (f32)
//   [12800, 25600)    epi_g: u64[1600] folded BN, permuted to d*25+v
//   [25600, 33792)    wv:    u16[4096] plain-W B-fragments (v-independent)
//   [33792, 40192)    combo_g: u32[1600] (gather_off<<16)|bf16(tanh(fm)+1)
//   [40192, ...)      part: f32[1216][3200] block partials (15.56 MB, optional)
constexpr int WS_EPI   = 12800;
constexpr int WS_WV    = 25600;
constexpr int WS_COMBO = 33792;
constexpr int WS_PART  = 40192;
constexpr size_t WS_NEED = (size_t)WS_PART + (size_t)NBLK * 3200 * 4;

__device__ __forceinline__ u16 f2b(float f) {
  u32 u = __float_as_uint(f);
  return (u16)((u + 0x7fffu + ((u >> 16) & 1u)) >> 16); // RNE
}
__device__ __forceinline__ float b2f(u16 h) {
  return __uint_as_float(((u32)h) << 16);
}
__device__ __forceinline__ u64 pack4(float a, float b, float c, float d) {
  return (u64)f2b(a) | ((u64)f2b(b) << 16) | ((u64)f2b(c) << 32) | ((u64)f2b(d) << 48);
}

// ---- stage x-tile as bf16, layout [c][t*25+v] (512 threads) ----
__device__ __forceinline__ void stage_raw(const float* __restrict__ x,
                                          int n, int t0, int validg, u16* raw) {
  const int base = n * 480000 + t0 * 25;
  if (validg == TBR * 25) {
    #pragma unroll
    for (int i = 0; i < 13; ++i) {
      int q = TID + i * 512;              // float4 group id, 0..6399
      if (q < 6400) {
        int c = q / 100;
        int g4 = (q - c * 100) * 4;       // 16B aligned
        float4 xv = *reinterpret_cast<const float4*>(x + base + c * 7500 + g4);
        *reinterpret_cast<u64*>(raw + q * 4) = pack4(xv.x, xv.y, xv.z, xv.w);
      }
    }
  } else {
    #pragma unroll
    for (int i = 0; i < 13; ++i) {
      int q = TID + i * 512;
      if (q < 6400) {
        int c = q / 100;
        int g4 = (q - c * 100) * 4;
        float4 xv = make_float4(0.f, 0.f, 0.f, 0.f);
        if (g4 < validg)                  // validg==300: 4-groups all-or-nothing
          xv = *reinterpret_cast<const float4*>(x + base + c * 7500 + g4);
        *reinterpret_cast<u64*>(raw + q * 4) = pack4(xv.x, xv.y, xv.z, xv.w);
      }
    }
  }
}

// 8 v-independent B fragments (plain W) -> registers, one coalesced pass
__device__ __forceinline__ void load_bfr_g(const u16* __restrict__ wv, bf16x8 bfr[2][4]) {
  int l = TID & 63;
  #pragma unroll
  for (int ks = 0; ks < 2; ++ks)
    #pragma unroll
    for (int nt = 0; nt < 4; ++nt)
      bfr[ks][nt] = *reinterpret_cast<const bf16x8*>(wv + ((((ks << 2) | nt) << 9) + l * 8));
}

// A fragment: gather+mask from LDS; combo table from L2; t=lane&15
__device__ __forceinline__ bf16x8 build_a(const u16* raw, const u32* __restrict__ combo,
                                          int v, int ks, int t, int grp) {
  int jb = v * 64 + ks * 32 + grp * 8;    // multiple of 8 -> 2x dwordx4
  bf16x8 a;
  #pragma unroll
  for (int i = 0; i < 8; ++i) {
    u32 cb = combo[jb + i];
    float m = __uint_as_float((cb & 0xffffu) << 16);
    float xv = b2f(raw[(cb >> 16) + t * 25]);
    a[i] = (__bf16)(xv * m);
  }
  return a;
}

// ---- precompute: zero wsum_final; combo (tanh hoisted); plain-W B fragments ----
__global__ void k_wv(const float* __restrict__ lin_w, const float* __restrict__ feat_mask,
                     const int* __restrict__ shift_in, float* __restrict__ wsum,
                     u16* __restrict__ wv, u32* __restrict__ combo_g) {
  int gid = blockIdx.x * 256 + TID;       // grid 13*256 = 3328
  if (gid < 3200) wsum[gid] = 0.f;        // atomic-mode target (must re-zero each launch)
  if (gid < Fin) {
    int s = shift_in[gid];                               // source col v2*64+c2
    u32 off = (u32)((s & 63) * 400 + (s >> 6));          // raw idx c2*400 + v2
    float m = tanhf(feat_mask[gid]) + 1.0f;
    combo_g[gid] = (off << 16) | (u32)f2b(m);
  }
  if (gid >= 2048 && gid < 2560) {        // 512 threads build B fragments
    int t = gid - 2048;
    int l = t & 63, nt = (t >> 6) & 3, ks = t >> 8;
    int c0 = ks * 32 + (l >> 4) * 8, d = nt * 16 + (l & 15);
    u16x8 o8;
    #pragma unroll
    for (int i = 0; i < 8; ++i) o8[i] = f2b(lin_w[(c0 + i) * 64 + d]);
    *reinterpret_cast<u16x8*>(wv + ((((ks << 2) | nt) << 9) + l * 8)) = o8;
  }
}

// ATOMIC=0: store block partial to part[bid][3200]; ATOMIC=1: atomicAdd into target
template <int ATOMIC>
__global__ __launch_bounds__(512, 6) void k_stats(
    const float* __restrict__ x, const u16* __restrict__ wv,
    const u32* __restrict__ combo_g, float* __restrict__ target)
{
  __shared__ __align__(16) u16 raw[RAWE];   // 51.2 KB -> 3 blocks/CU
  bf16x8 bfr[2][4];
  load_bfr_g(wv, bfr);

  int bid = blockIdx.x;                   // 0..1215, 1 tile each
  int n = bid / NTB, tb = bid - n * NTB;
  int t0 = tb * TBR;
  int validg = min(TBR, Tt - t0) * 25;
  int w = TID >> 6, l = TID & 63;
  int t_lane = l & 15, grp = l >> 4;

  stage_raw(x, n, t0, validg, raw);
  __syncthreads();

  float* pb = target + (ATOMIC ? 0 : bid * 3200);
  #pragma unroll
  for (int k = 0; k < 4; ++k) {
    int v = w + 8 * k;
    if (v < Vv) {
      bf16x8 a0 = build_a(raw, combo_g, v, 0, t_lane, grp);
      bf16x8 a1 = build_a(raw, combo_g, v, 1, t_lane, grp);
      float pr[4], qr[4];
      #pragma unroll
      for (int nt = 0; nt < 4; ++nt) {
        f32x4 acc = {0.f, 0.f, 0.f, 0.f};
        acc = __builtin_amdgcn_mfma_f32_16x16x32_bf16(a0, bfr[0][nt], acc, 0, 0, 0);
        acc = __builtin_amdgcn_mfma_f32_16x16x32_bf16(a1, bfr[1][nt], acc, 0, 0, 0);
        // zero-padded t rows contribute 0 to both sums
        float pp = acc[0] + acc[1] + acc[2] + acc[3];
        float qq = acc[0]*acc[0] + acc[1]*acc[1] + acc[2]*acc[2] + acc[3]*acc[3];
        pp += __shfl_xor(pp, 16); pp += __shfl_xor(pp, 32);   // all-reduce
        qq += __shfl_xor(qq, 16); qq += __shfl_xor(qq, 32);
        pr[nt] = pp; qr[nt] = qq;
      }
      if (ATOMIC) {
        if ((l & 48) == 0) {
          #pragma unroll
          for (int nt = 0; nt < 4; ++nt) {
            int col = v * 64 + nt * 16 + t_lane;
            atomicAdd(&pb[col], pr[nt]);
            atomicAdd(&pb[1600 + col], qr[nt]);
          }
        }
      } else {
        // lane l holds fragment grp=l>>4 -> full-wave 256B coalesced stores
        float pv = (grp & 2) ? ((grp & 1) ? pr[3] : pr[2]) : ((grp & 1) ? pr[1] : pr[0]);
        float qv = (grp & 2) ? ((grp & 1) ? qr[3] : qr[2]) : ((grp & 1) ? qr[1] : qr[0]);
        pb[v * 64 + l] = pv;
        pb[1600 + v * 64 + l] = qv;
      }
    }
  }
}

// reduce part[1216][3200] -> wsum_final[3200]; 200 blocks x (16 cols x 16 chunks)
__global__ __launch_bounds__(256) void k_red(const float* __restrict__ part,
                                             float* __restrict__ wsum) {
  __shared__ float red[16 * 17];
  int col0 = blockIdx.x * 16;
  int c = TID & 15, ch = TID >> 4;        // ch 0..15, 76 rows each
  float s = 0.f;
  int r0 = ch * 76;
  #pragma unroll 4
  for (int i = 0; i < 76; ++i) s += part[(r0 + i) * 3200 + col0 + c];
  red[ch * 17 + c] = s;
  __syncthreads();
  if (TID < 16) {
    float t = 0.f;
    #pragma unroll
    for (int j = 0; j < 16; ++j) t += red[j * 17 + TID];
    wsum[col0 + TID] = t;
  }
}

// BN fold once: entry {f32 scale, bf16 off, u16 s2*YP} at permuted index d*25+v
__global__ void k_epi(const float* __restrict__ wsum, const float* __restrict__ gamma,
                      const float* __restrict__ beta, const int* __restrict__ shift_out,
                      u64* __restrict__ epi_g) {
  int k = blockIdx.x * 256 + TID;
  if (k >= Fin) return;
  int s2 = shift_out[k];
  float sm = wsum[s2] * (1.0f / RowsT);
  float sq = wsum[1600 + s2] * (1.0f / RowsT);
  float rstd = rsqrtf(fmaxf(sq - sm * sm, 0.f) + EPSv);
  float sc = gamma[k] * rstd;             // lin_b provably cancels in BN
  int d = k & 63, v = k >> 6;
  epi_g[d * 25 + v] = (u64)__float_as_uint(sc)
                    | ((u64)f2b(beta[k] - sm * sc) << 32)
                    | ((u64)(u32)(s2 * YP) << 48);
}

__global__ __launch_bounds__(512, 4) void k_main(
    const float* __restrict__ x, const u16* __restrict__ wv,
    const u32* __restrict__ combo_g, const u64* __restrict__ epi_g,
    float* __restrict__ out)
{
  // [0,51200) raw | [51200,57600) combo  --(after hoist sync)--> ylds [0,67200)
  // epi [67200,80000) persistent
  __shared__ __align__(16) unsigned char smem[80000];
  u16* raw   = reinterpret_cast<u16*>(smem);
  u32* combo = reinterpret_cast<u32*>(smem + 51200);
  u16* ylds  = reinterpret_cast<u16*>(smem);
  u64* epi   = reinterpret_cast<u64*>(smem + 67200);

  int bid = blockIdx.x;
  int n = bid / NTB, tb = bid - n * NTB;
  int t0 = tb * TBR;
  int validg = min(TBR, Tt - t0) * 25;

  bf16x8 bfr[2][4];
  load_bfr_g(wv, bfr);
  stage_raw(x, n, t0, validg, raw);
  #pragma unroll
  for (int i = 0; i < 4; ++i) {
    int j = TID + i * 512;
    if (j < Fin) {
      combo[j] = combo_g[j];
      epi[j] = epi_g[j];
    }
  }
  __syncthreads();

  // hoist A fragments to registers; raw+combo die after this
  int w = TID >> 6, l = TID & 63, grp = l >> 4, t_lane = l & 15;
  bf16x8 areg[4][2];
  #pragma unroll
  for (int k = 0; k < 4; ++k) {
    int v = w + 8 * k;
    if (v < Vv) {
      areg[k][0] = build_a(raw, combo, v, 0, t_lane, grp);
      areg[k][1] = build_a(raw, combo, v, 1, t_lane, grp);
    }
  }
  __syncthreads();  // overlay region now ylds

  #pragma unroll
  for (int k = 0; k < 4; ++k) {
    int v = w + 8 * k;
    if (v < Vv) {
      #pragma unroll
      for (int nt = 0; nt < 4; ++nt) {
        f32x4 acc = {0.f, 0.f, 0.f, 0.f};
        acc = __builtin_amdgcn_mfma_f32_16x16x32_bf16(areg[k][0], bfr[0][nt], acc, 0, 0, 0);
        acc = __builtin_amdgcn_mfma_f32_16x16x32_bf16(areg[k][1], bfr[1][nt], acc, 0, 0, 0);
        int o = (v * 64 + nt * 16 + t_lane) * YP + grp * 4;   // rows t = grp*4+j
        #pragma unroll
        for (int j = 0; j < 4; ++j) ylds[o + j] = f2b(acc[j]);
      }
    }
  }
  __syncthreads();

  // epilogue: BN + residual (x re-read, L3-hot) + relu, float4 stores
  const int obase = n * 480000 + t0 * 25;
  #pragma unroll
  for (int it = 0; it < 13; ++it) {
    int g = TID + it * 512;               // float4 group id
    if (g < 6400) {
      int d = g / 100;
      int f0 = (g - d * 100) * 4;
      if (f0 < validg) {
        const float4 xr = *reinterpret_cast<const float4*>(x + obase + d * 7500 + f0);
        float4 o;
        float* op = &o.x;
        const float* xp = &xr.x;
        #pragma unroll
        for (int e = 0; e < 4; ++e) {
          int f = f0 + e;
          int t = f / 25;
          int v = f - t * 25;
          u64 ep = epi[d * 25 + v];
          float sc = __uint_as_float((u32)ep);
          float of = b2f((u16)(ep >> 32));
          float y = b2f(ylds[(int)(ep >> 48) + t]);
          op[e] = fmaxf(fmaf(y, sc, of) + xp[e], 0.f);
        }
        *reinterpret_cast<float4*>(out + obase + d * 7500 + f0) = o;
      }
    }
  }
}

extern "C" void kernel_launch(void* const* d_in, const int* in_sizes, int n_in,
                              void* d_out, int out_size, void* d_ws, size_t ws_size,
                              hipStream_t stream) {
  (void)in_sizes; (void)n_in; (void)out_size;
  const float* x        = (const float*)d_in[0];
  const float* lin_w    = (const float*)d_in[1];
  // d_in[2] = lin_b: provably cancels in BatchNorm -> unused
  const float* feat_mask= (const float*)d_in[3];
  const float* gamma    = (const float*)d_in[4];
  const float* beta     = (const float*)d_in[5];
  const int*   shift_in = (const int*)d_in[6];
  const int*   shift_out= (const int*)d_in[7];
  float* wsum   = (float*)d_ws;
  u64*   epi_g  = (u64*)((char*)d_ws + WS_EPI);
  u16*   wv     = (u16*)((char*)d_ws + WS_WV);
  u32*   combo_g= (u32*)((char*)d_ws + WS_COMBO);
  float* part   = (float*)((char*)d_ws + WS_PART);

  k_wv<<<13, 256, 0, stream>>>(lin_w, feat_mask, shift_in, wsum, wv, combo_g);
  if (ws_size >= WS_NEED) {
    k_stats<0><<<NBLK, 512, 0, stream>>>(x, wv, combo_g, part);
    k_red<<<200, 256, 0, stream>>>(part, wsum);
  } else {
    k_stats<1><<<NBLK, 512, 0, stream>>>(x, wv, combo_g, wsum);
  }
  k_epi  <<<7, 256, 0, stream>>>(wsum, gamma, beta, shift_out, epi_g);
  k_main <<<NBLK, 512, 0, stream>>>(x, wv, combo_g, epi_g, (float*)d_out);
}